// Round 9
// baseline (528.294 us; speedup 1.0000x reference)
//
#include <hip/hip_runtime.h>
#include <stdint.h>
#include <stddef.h>

// ---------- types ----------
typedef _Float16 half_t;
typedef half_t half8  __attribute__((ext_vector_type(8)));
typedef half_t half4v __attribute__((ext_vector_type(4)));
typedef float  f32x4  __attribute__((ext_vector_type(4)));

__device__ __forceinline__ float fast_sigmoid(float x) {
    float e = __builtin_amdgcn_exp2f(-1.44269504f * x);
    return __builtin_amdgcn_rcpf(1.0f + e);
}
__device__ __forceinline__ float fast_tanh(float x) {
    float e = __builtin_amdgcn_exp2f(2.88539008f * x);
    return 1.0f - 2.0f * __builtin_amdgcn_rcpf(1.0f + e);
}

// ---------------------------------------------------------------------------
// Prep: W [1024][256] f32 row-major -> MFMA-B fragment order, f16.
// Bijection (contiguous k): lane l, elem e of tile (T,kt) holds
//   B[k = kt*32 + (l>>4)*8 + e, j = T*16 + (l&15)].
// A-fragments from LDS use the SAME (lane-group,elem)->k mapping (validated
// R1-R8: absmax 2e-3).
// ---------------------------------------------------------------------------
__global__ __launch_bounds__(64) void shuffle_w_kernel(
    const float* __restrict__ W, half_t* __restrict__ out)
{
    const int blk = blockIdx.x;         // 512 = 64 T * 8 kt
    const int T = blk >> 3, kt = blk & 7;
    const int l = threadIdx.x;
    const int j = T * 16 + (l & 15);
    const int k0 = kt * 32 + ((l >> 4) << 3);
    half8 v;
#pragma unroll
    for (int e = 0; e < 8; ++e) v[e] = (half_t)W[j * 256 + k0 + e];
    *reinterpret_cast<half8*>(out + (size_t)(blk * 64 + l) * 8) = v;
}

// ---------------------------------------------------------------------------
// Single-pass 4-gate GEMM: acc[mt*8 + g*2 + j] += hx(64x256) @ W^T tile
// (g*16 + w*2 + j).  kt loop PINNED (unroll 1 + sched_barrier): caps the
// transient in-flight load set (R4-R8 evidence: pinned ~12 spill slots,
// unpinned ~80).
// ---------------------------------------------------------------------------
__device__ __forceinline__ void gemm_all(
    f32x4* acc, const half_t* __restrict__ lhx,
    const half_t* __restrict__ Ws, int w, int lm, int lg, int l)
{
#pragma unroll 1
    for (int kt = 0; kt < 8; ++kt) {
        half8 a[4];
#pragma unroll
        for (int mt = 0; mt < 4; ++mt) {
            const int p = mt * 16 + lm;
            const int k = (kt * 32 + lg * 8) ^ ((p & 7) << 4);
            a[mt] = *reinterpret_cast<const half8*>(&lhx[p * 256 + k]);
        }
#pragma unroll
        for (int g = 0; g < 4; ++g)
#pragma unroll
            for (int j = 0; j < 2; ++j) {
                const int T = g * 16 + w * 2 + j;
                half8 b = *reinterpret_cast<const half8*>(
                    &Ws[(size_t)((T * 8 + kt) * 64 + l) * 8]);
#pragma unroll
                for (int mt = 0; mt < 4; ++mt)
                    acc[mt * 8 + g * 2 + j] = __builtin_amdgcn_mfma_f32_16x16x32_f16(
                        a[mt], b, acc[mt * 8 + g * 2 + j], 0, 0, 0);
            }
        __builtin_amdgcn_sched_barrier(0);   // no motion across kt iterations
    }
}

// ---------------------------------------------------------------------------
// Persistent LSTM: block = 64 rows x 16 steps, 8 waves (512 threads).
// R9 pressure ledger (unified 256/wave at 2 waves/SIMD):
//   acc 128 (AGPR) + xp 64 (x_proj IS thread-local -- the R1-R8 lds_xp
//   round-trip was pure overhead) + a 16 + b 8-16 + addr ~15 = ~231-239.
//   cx moved to LDS (thread-private f32 slots, 2-way bank alias = free)
//   to take 32 regs off the arch side.
// LDS: hx 32 KB (XOR-swizzled) + cx 64 KB = 96 KB, 1 block/CU, 2 waves/SIMD.
// ---------------------------------------------------------------------------
__global__ __launch_bounds__(512, 2) void lstm_kernel(
    const float* __restrict__ x,      // [8][256][1600]
    const float* __restrict__ hx0,    // [12800][256]
    const float* __restrict__ cx0,    // [12800][256]
    const float* __restrict__ b_ih,   // [1024]
    const float* __restrict__ b_hh,   // [1024]
    const float* __restrict__ W_lin,  // [2][256]
    const float* __restrict__ b_lin,  // [2]
    const half_t* __restrict__ Wih_s, // shuffled f16
    const half_t* __restrict__ Whh_s, // shuffled f16
    float* __restrict__ out)          // [12800][16][2]
{
    __shared__ __align__(16) half_t lds_hx[64 * 256];   // 32 KB
    __shared__ __align__(16) float  cx_lds[32 * 512];   // 64 KB, [slot][tid]

    const int tid = threadIdx.x;
    const int w  = tid >> 6;   // wave 0..7 owns h-cols [w*32, w*32+32)
    const int l  = tid & 63;
    const int lm = l & 15;
    const int lg = l >> 4;

    const int row0 = blockIdx.x * 64;     // 200 blocks * 64 rows
    const int bb_  = row0 / 1600;
    const int p0   = row0 % 1600;

    // ---- stage x tile into lds_hx, f16 swizzled (coalesced on p) ----
    {
        const float* xin = x + (size_t)bb_ * 409600 + p0;   // x[b][c][p0+p]
        for (int it = 0; it < 32; ++it) {
            int idx = it * 512 + tid;
            int p = idx & 63, c = idx >> 6;
            lds_hx[p * 256 + (c ^ ((p & 7) << 4))] = (half_t)xin[c * 1600 + p];
        }
    }
    __syncthreads();

    f32x4 acc[32];

    // ---------------- phase 0: x_proj = x @ W_ih^T + b_ih + b_hh ----------
#pragma unroll
    for (int g = 0; g < 4; ++g)
#pragma unroll
        for (int j = 0; j < 2; ++j) {
            int col = g * 256 + (w * 2 + j) * 16 + lm;
            float bias = b_ih[col] + b_hh[col];
#pragma unroll
            for (int mt = 0; mt < 4; ++mt)
                acc[mt * 8 + g * 2 + j] = (f32x4){bias, bias, bias, bias};
        }
    gemm_all(acc, lds_hx, Wih_s, w, lm, lg, l);

    // pack x_proj into thread-local f16 registers (NO LDS round-trip)
    half4v xp[32];
#pragma unroll
    for (int f = 0; f < 32; ++f)
#pragma unroll
        for (int r = 0; r < 4; ++r) xp[f][r] = (half_t)acc[f][r];

    __syncthreads();   // x tile fully consumed; lds_hx reusable

    // ---- stage h0 into lds_hx (coalesced on c); cx into LDS slots ----
    {
        const float* hin = hx0 + (size_t)row0 * 256;
        for (int it = 0; it < 32; ++it) {
            int idx = it * 512 + tid;
            int c = idx & 255, p = idx >> 8;
            lds_hx[p * 256 + (c ^ ((p & 7) << 4))] = (half_t)hin[p * 256 + c];
        }
    }
#pragma unroll
    for (int mt = 0; mt < 4; ++mt)
#pragma unroll
        for (int j = 0; j < 2; ++j)
#pragma unroll
            for (int r = 0; r < 4; ++r) {
                int p = mt * 16 + lg * 4 + r;
                int c = w * 32 + j * 16 + lm;
                cx_lds[((mt * 2 + j) * 4 + r) * 512 + tid] =
                    cx0[(size_t)(row0 + p) * 256 + c];
            }
    __syncthreads();

    // ---------------- 16 recurrent steps ----------------
#pragma unroll 1
    for (int t = 0; t < 16; ++t) {
        // phase 1: acc init = x_proj (pure in-register cvt, no LDS)
#pragma unroll
        for (int f = 0; f < 32; ++f)
#pragma unroll
            for (int r = 0; r < 4; ++r) acc[f][r] = (float)xp[f][r];
        __builtin_amdgcn_sched_barrier(0);

        // phase 2: GEMM (kt-pinned inside)
        gemm_all(acc, lds_hx, Whh_s, w, lm, lg, l);

        __syncthreads();   // all waves finished reading lds_hx(t)

        // phase 3: cell update; cx in LDS (thread-private slots),
        // write hx(t+1) into lds_hx (f16, swizzled)
#pragma unroll
        for (int mt = 0; mt < 4; ++mt)
#pragma unroll
            for (int j = 0; j < 2; ++j)
#pragma unroll
                for (int r = 0; r < 4; ++r) {
                    const int slot = ((mt * 2 + j) * 4 + r) * 512 + tid;
                    float iv = acc[mt * 8 + 0 + j][r];
                    float fv = acc[mt * 8 + 2 + j][r];
                    float gv = acc[mt * 8 + 4 + j][r];
                    float ov = acc[mt * 8 + 6 + j][r];
                    float cxn = fast_sigmoid(fv) * cx_lds[slot] +
                                fast_sigmoid(iv) * fast_tanh(gv);
                    cx_lds[slot] = cxn;
                    float h = fast_sigmoid(ov) * fast_tanh(cxn);
                    int p  = mt * 16 + lg * 4 + r;
                    int cc = w * 32 + j * 16 + lm;
                    lds_hx[p * 256 + (cc ^ ((p & 7) << 4))] = (half_t)h;
                }
        __syncthreads();   // hx(t+1) visible to all

        // phase 4: head y = leaky_relu(hx) @ W_lin^T + b_lin -> [n][t][o]
        {
            const int p = tid >> 3;          // row 0..63
            const int o = (tid >> 2) & 1;    // output 0..1
            const int q = tid & 3;           // quarter of the 256 h-cols
            const float* wl = W_lin + o * 256;
            float s = 0.0f;
#pragma unroll
            for (int cb = 0; cb < 16; ++cb) {
                int c0 = q * 64 + cb * 4;
                half4v u = *reinterpret_cast<const half4v*>(
                    &lds_hx[p * 256 + (c0 ^ ((p & 7) << 4))]);
                float4 wv = *reinterpret_cast<const float4*>(wl + c0);
                float h0 = (float)u[0], h1 = (float)u[1];
                float h2 = (float)u[2], h3 = (float)u[3];
                s += fmaxf(h0, 0.01f * h0) * wv.x;
                s += fmaxf(h1, 0.01f * h1) * wv.y;
                s += fmaxf(h2, 0.01f * h2) * wv.z;
                s += fmaxf(h3, 0.01f * h3) * wv.w;
            }
            s += __shfl_xor(s, 1);
            s += __shfl_xor(s, 2);
            if (q == 0)
                out[((size_t)(row0 + p) * 16 + t) * 2 + o] = s + b_lin[o];
        }
    }
}

// ---------------------------------------------------------------------------
extern "C" void kernel_launch(void* const* d_in, const int* in_sizes, int n_in,
                              void* d_out, int out_size, void* d_ws, size_t ws_size,
                              hipStream_t stream)
{
    const float* x    = (const float*)d_in[0];
    const float* hx   = (const float*)d_in[1];
    const float* cx   = (const float*)d_in[2];
    const float* Wih  = (const float*)d_in[3];
    const float* Whh  = (const float*)d_in[4];
    const float* bih  = (const float*)d_in[5];
    const float* bhh  = (const float*)d_in[6];
    const float* Wlin = (const float*)d_in[7];
    const float* blin = (const float*)d_in[8];
    float* out = (float*)d_out;

    half_t* wih_s = (half_t*)d_ws;             // 512 KB
    half_t* whh_s = wih_s + 1024 * 256;        // 512 KB

    shuffle_w_kernel<<<512, 64, 0, stream>>>(Wih, wih_s);
    shuffle_w_kernel<<<512, 64, 0, stream>>>(Whh, whh_s);
    lstm_kernel<<<200, 512, 0, stream>>>(x, hx, cx, bih, bhh, Wlin, blin,
                                         wih_s, whh_s, out);
}

// Round 10
// 419.542 us; speedup vs baseline: 1.2592x; 1.2592x over previous
//
#include <hip/hip_runtime.h>
#include <stdint.h>
#include <stddef.h>

// ---------- types ----------
typedef _Float16 half_t;
typedef half_t half8  __attribute__((ext_vector_type(8)));
typedef half_t half4v __attribute__((ext_vector_type(4)));
typedef float  f32x4  __attribute__((ext_vector_type(4)));

__device__ __forceinline__ float fast_sigmoid(float x) {
    float e = __builtin_amdgcn_exp2f(-1.44269504f * x);
    return __builtin_amdgcn_rcpf(1.0f + e);
}
__device__ __forceinline__ float fast_tanh(float x) {
    float e = __builtin_amdgcn_exp2f(2.88539008f * x);
    return 1.0f - 2.0f * __builtin_amdgcn_rcpf(1.0f + e);
}

// ---------------------------------------------------------------------------
// Prep: W [1024][256] f32 row-major -> MFMA-B fragment order, f16.
// Bijection (contiguous k): lane l, elem e of tile (T,kt) holds
//   B[k = kt*32 + (l>>4)*8 + e, j = T*16 + (l&15)].
// A-fragments from LDS use the SAME (lane-group,elem)->k mapping (validated
// R1-R9: absmax 2e-3).
// ---------------------------------------------------------------------------
__global__ __launch_bounds__(64) void shuffle_w_kernel(
    const float* __restrict__ W, half_t* __restrict__ out)
{
    const int blk = blockIdx.x;         // 512 = 64 T * 8 kt
    const int T = blk >> 3, kt = blk & 7;
    const int l = threadIdx.x;
    const int j = T * 16 + (l & 15);
    const int k0 = kt * 32 + ((l >> 4) << 3);
    half8 v;
#pragma unroll
    for (int e = 0; e < 8; ++e) v[e] = (half_t)W[j * 256 + k0 + e];
    *reinterpret_cast<half8*>(out + (size_t)(blk * 64 + l) * 8) = v;
}

// ---------------------------------------------------------------------------
// Single-pass 4-gate GEMM: acc[mt*8 + g*2 + j] += hx(64x256) @ W^T tile
// (g*16 + w*2 + j).  kt loop PINNED (unroll 1 + sched_barrier): caps the
// transient in-flight load set (R4-R9 evidence).
// ---------------------------------------------------------------------------
__device__ __forceinline__ void gemm_all(
    f32x4* acc, const half_t* __restrict__ lhx,
    const half_t* __restrict__ Ws, int w, int lm, int lg, int l)
{
#pragma unroll 1
    for (int kt = 0; kt < 8; ++kt) {
        half8 a[4];
#pragma unroll
        for (int mt = 0; mt < 4; ++mt) {
            const int p = mt * 16 + lm;
            const int k = (kt * 32 + lg * 8) ^ ((p & 7) << 4);
            a[mt] = *reinterpret_cast<const half8*>(&lhx[p * 256 + k]);
        }
#pragma unroll
        for (int g = 0; g < 4; ++g)
#pragma unroll
            for (int j = 0; j < 2; ++j) {
                const int T = g * 16 + w * 2 + j;
                half8 b = *reinterpret_cast<const half8*>(
                    &Ws[(size_t)((T * 8 + kt) * 64 + l) * 8]);
#pragma unroll
                for (int mt = 0; mt < 4; ++mt)
                    acc[mt * 8 + g * 2 + j] = __builtin_amdgcn_mfma_f32_16x16x32_f16(
                        a[mt], b, acc[mt * 8 + g * 2 + j], 0, 0, 0);
            }
        __builtin_amdgcn_sched_barrier(0);   // no motion across kt iterations
    }
}

// ---------------------------------------------------------------------------
// Persistent LSTM: block = 64 rows x 16 steps, 8 waves (512 threads).
// KEY FIX (R10): amdgpu_waves_per_eu(2,2). VGPR_Count has equalled
// 2048/(2-blocks-worth-of-waves) in ALL of R2-R9 -- the compiler budgets
// registers for 2 blocks/CU although our LDS (96-160 KB) limits us to 1.
// Pinning 2 waves/EU raises the budget 128 -> 256/wave:
//   acc 128 + xp 64 + a 16 + b 8 + addr ~20 = ~236 <= 256  -> no spills.
// LDS: hx 32 KB (XOR-swizzled) + cx 64 KB (thread-private f32 slots,
// 2-way bank alias = free) + W_lin 2.2 KB padded = ~98 KB, 1 block/CU.
// ---------------------------------------------------------------------------
__global__ __launch_bounds__(512)
__attribute__((amdgpu_waves_per_eu(2, 2)))
void lstm_kernel(
    const float* __restrict__ x,      // [8][256][1600]
    const float* __restrict__ hx0,    // [12800][256]
    const float* __restrict__ cx0,    // [12800][256]
    const float* __restrict__ b_ih,   // [1024]
    const float* __restrict__ b_hh,   // [1024]
    const float* __restrict__ W_lin,  // [2][256]
    const float* __restrict__ b_lin,  // [2]
    const half_t* __restrict__ Wih_s, // shuffled f16
    const half_t* __restrict__ Whh_s, // shuffled f16
    float* __restrict__ out)          // [12800][16][2]
{
    __shared__ __align__(16) half_t lds_hx[64 * 256];   // 32 KB
    __shared__ __align__(16) float  cx_lds[32 * 512];   // 64 KB, [slot][tid]
    __shared__ __align__(16) float  wlin_lds[2 * 272];  // padded: o*272+q*68+ci

    const int tid = threadIdx.x;
    const int w  = tid >> 6;   // wave 0..7 owns h-cols [w*32, w*32+32)
    const int l  = tid & 63;
    const int lm = l & 15;
    const int lg = l >> 4;

    const int row0 = blockIdx.x * 64;     // 200 blocks * 64 rows
    const int bb_  = row0 / 1600;
    const int p0   = row0 % 1600;

    // ---- stage x tile into lds_hx (f16 swizzled) + W_lin into padded LDS --
    {
        const float* xin = x + (size_t)bb_ * 409600 + p0;   // x[b][c][p0+p]
        for (int it = 0; it < 32; ++it) {
            int idx = it * 512 + tid;
            int p = idx & 63, c = idx >> 6;
            lds_hx[p * 256 + (c ^ ((p & 7) << 4))] = (half_t)xin[c * 1600 + p];
        }
        // W_lin: 512 floats, one per thread; pad so the head's 8 distinct
        // (o,q) float4 reads hit 8 distinct bank-quads (conflict-free).
        int o = tid >> 8, c = tid & 255, q = c >> 6, ci = c & 63;
        wlin_lds[o * 272 + q * 68 + ci] = W_lin[tid];
    }
    __syncthreads();

    f32x4 acc[32];

    // ---------------- phase 0: x_proj = x @ W_ih^T + b_ih + b_hh ----------
#pragma unroll
    for (int g = 0; g < 4; ++g)
#pragma unroll
        for (int j = 0; j < 2; ++j) {
            int col = g * 256 + (w * 2 + j) * 16 + lm;
            float bias = b_ih[col] + b_hh[col];
#pragma unroll
            for (int mt = 0; mt < 4; ++mt)
                acc[mt * 8 + g * 2 + j] = (f32x4){bias, bias, bias, bias};
        }
    gemm_all(acc, lds_hx, Wih_s, w, lm, lg, l);

    // pack x_proj into thread-local f16 registers (no LDS round-trip)
    half4v xp[32];
#pragma unroll
    for (int f = 0; f < 32; ++f)
#pragma unroll
        for (int r = 0; r < 4; ++r) xp[f][r] = (half_t)acc[f][r];

    __syncthreads();   // x tile fully consumed; lds_hx reusable

    // ---- stage h0 into lds_hx (coalesced on c); cx into LDS slots ----
    {
        const float* hin = hx0 + (size_t)row0 * 256;
        for (int it = 0; it < 32; ++it) {
            int idx = it * 512 + tid;
            int c = idx & 255, p = idx >> 8;
            lds_hx[p * 256 + (c ^ ((p & 7) << 4))] = (half_t)hin[p * 256 + c];
        }
    }
#pragma unroll
    for (int mt = 0; mt < 4; ++mt)
#pragma unroll
        for (int j = 0; j < 2; ++j)
#pragma unroll
            for (int r = 0; r < 4; ++r) {
                int p = mt * 16 + lg * 4 + r;
                int c = w * 32 + j * 16 + lm;
                cx_lds[((mt * 2 + j) * 4 + r) * 512 + tid] =
                    cx0[(size_t)(row0 + p) * 256 + c];
            }
    const float blin0 = b_lin[0], blin1 = b_lin[1];
    __syncthreads();

    // ---------------- 16 recurrent steps ----------------
#pragma unroll 1
    for (int t = 0; t < 16; ++t) {
        // phase 1: acc init = x_proj (pure in-register cvt)
#pragma unroll
        for (int f = 0; f < 32; ++f)
#pragma unroll
            for (int r = 0; r < 4; ++r) acc[f][r] = (float)xp[f][r];
        __builtin_amdgcn_sched_barrier(0);

        // phase 2: GEMM (kt-pinned inside)
        gemm_all(acc, lds_hx, Whh_s, w, lm, lg, l);

        __syncthreads();   // all waves finished reading lds_hx(t)

        // phase 3: cell update; cx in LDS slots; hx(t+1) -> lds_hx swizzled
#pragma unroll
        for (int mt = 0; mt < 4; ++mt)
#pragma unroll
            for (int j = 0; j < 2; ++j)
#pragma unroll
                for (int r = 0; r < 4; ++r) {
                    const int slot = ((mt * 2 + j) * 4 + r) * 512 + tid;
                    float iv = acc[mt * 8 + 0 + j][r];
                    float fv = acc[mt * 8 + 2 + j][r];
                    float gv = acc[mt * 8 + 4 + j][r];
                    float ov = acc[mt * 8 + 6 + j][r];
                    float cxn = fast_sigmoid(fv) * cx_lds[slot] +
                                fast_sigmoid(iv) * fast_tanh(gv);
                    cx_lds[slot] = cxn;
                    float h = fast_sigmoid(ov) * fast_tanh(cxn);
                    int p  = mt * 16 + lg * 4 + r;
                    int cc = w * 32 + j * 16 + lm;
                    lds_hx[p * 256 + (cc ^ ((p & 7) << 4))] = (half_t)h;
                }
        __builtin_amdgcn_sched_barrier(0);
        __syncthreads();   // hx(t+1) visible to all

        // phase 4: head y = leaky_relu(hx) @ W_lin^T + b_lin -> [n][t][o]
        {
            const int p = tid >> 3;          // row 0..63
            const int o = (tid >> 2) & 1;    // output 0..1
            const int q = tid & 3;           // quarter of the 256 h-cols
            const float* wl = &wlin_lds[o * 272 + q * 68];
            float s = 0.0f;
#pragma unroll 2
            for (int cb = 0; cb < 16; ++cb) {
                int c0 = q * 64 + cb * 4;
                half4v u = *reinterpret_cast<const half4v*>(
                    &lds_hx[p * 256 + (c0 ^ ((p & 7) << 4))]);
                float4 wv = *reinterpret_cast<const float4*>(wl + cb * 4);
                float h0 = (float)u[0], h1 = (float)u[1];
                float h2 = (float)u[2], h3 = (float)u[3];
                s += fmaxf(h0, 0.01f * h0) * wv.x;
                s += fmaxf(h1, 0.01f * h1) * wv.y;
                s += fmaxf(h2, 0.01f * h2) * wv.z;
                s += fmaxf(h3, 0.01f * h3) * wv.w;
            }
            s += __shfl_xor(s, 1);
            s += __shfl_xor(s, 2);
            if (q == 0)
                out[((size_t)(row0 + p) * 16 + t) * 2 + o] =
                    s + (o ? blin1 : blin0);
        }
        __builtin_amdgcn_sched_barrier(0);
    }
}

// ---------------------------------------------------------------------------
extern "C" void kernel_launch(void* const* d_in, const int* in_sizes, int n_in,
                              void* d_out, int out_size, void* d_ws, size_t ws_size,
                              hipStream_t stream)
{
    const float* x    = (const float*)d_in[0];
    const float* hx   = (const float*)d_in[1];
    const float* cx   = (const float*)d_in[2];
    const float* Wih  = (const float*)d_in[3];
    const float* Whh  = (const float*)d_in[4];
    const float* bih  = (const float*)d_in[5];
    const float* bhh  = (const float*)d_in[6];
    const float* Wlin = (const float*)d_in[7];
    const float* blin = (const float*)d_in[8];
    float* out = (float*)d_out;

    half_t* wih_s = (half_t*)d_ws;             // 512 KB
    half_t* whh_s = wih_s + 1024 * 256;        // 512 KB

    shuffle_w_kernel<<<512, 64, 0, stream>>>(Wih, wih_s);
    shuffle_w_kernel<<<512, 64, 0, stream>>>(Whh, whh_s);
    lstm_kernel<<<200, 512, 0, stream>>>(x, hx, cx, bih, bhh, Wlin, blin,
                                         wih_s, whh_s, out);
}

// Round 11
// 320.838 us; speedup vs baseline: 1.6466x; 1.3076x over previous
//
#include <hip/hip_runtime.h>
#include <stdint.h>
#include <stddef.h>

// ---------- types ----------
typedef _Float16 half_t;
typedef half_t half8  __attribute__((ext_vector_type(8)));
typedef half_t half4v __attribute__((ext_vector_type(4)));
typedef float  f32x4  __attribute__((ext_vector_type(4)));

__device__ __forceinline__ float fast_sigmoid(float x) {
    float e = __builtin_amdgcn_exp2f(-1.44269504f * x);
    return __builtin_amdgcn_rcpf(1.0f + e);
}
__device__ __forceinline__ float fast_tanh(float x) {
    float e = __builtin_amdgcn_exp2f(2.88539008f * x);
    return 1.0f - 2.0f * __builtin_amdgcn_rcpf(1.0f + e);
}

// ---------------------------------------------------------------------------
// Prep: W [1024][256] f32 row-major -> MFMA-B fragment order, f16.
// Bijection (contiguous k): lane l, elem e of tile (T,kt) holds
//   B[k = kt*32 + (l>>4)*8 + e, j = T*16 + (l&15)].
// A-fragments from LDS use the SAME (lane-group,elem)->k mapping (validated
// R1-R10: absmax 2e-3).
// ---------------------------------------------------------------------------
__global__ __launch_bounds__(64) void shuffle_w_kernel(
    const float* __restrict__ W, half_t* __restrict__ out)
{
    const int blk = blockIdx.x;         // 512 = 64 T * 8 kt
    const int T = blk >> 3, kt = blk & 7;
    const int l = threadIdx.x;
    const int j = T * 16 + (l & 15);
    const int k0 = kt * 32 + ((l >> 4) << 3);
    half8 v;
#pragma unroll
    for (int e = 0; e < 8; ++e) v[e] = (half_t)W[j * 256 + k0 + e];
    *reinterpret_cast<half8*>(out + (size_t)(blk * 64 + l) * 8) = v;
}

// ---------------------------------------------------------------------------
// Single-pass 4-gate GEMM: acc[mt*8 + g*2 + j] += hx(64x256) @ W^T tile
// (g*16 + w*2 + j).  kt loop PINNED (unroll 1 + sched_barrier): caps the
// transient in-flight load set (R4-R10 evidence: pinned spills ~order less).
// ---------------------------------------------------------------------------
__device__ __forceinline__ void gemm_all(
    f32x4* acc, const half_t* __restrict__ lhx,
    const half_t* __restrict__ Ws, int w, int lm, int lg, int l)
{
#pragma unroll 1
    for (int kt = 0; kt < 8; ++kt) {
        half8 a[4];
#pragma unroll
        for (int mt = 0; mt < 4; ++mt) {
            const int p = mt * 16 + lm;
            const int k = (kt * 32 + lg * 8) ^ ((p & 7) << 4);
            a[mt] = *reinterpret_cast<const half8*>(&lhx[p * 256 + k]);
        }
#pragma unroll
        for (int g = 0; g < 4; ++g)
#pragma unroll
            for (int j = 0; j < 2; ++j) {
                const int T = g * 16 + w * 2 + j;
                half8 b = *reinterpret_cast<const half8*>(
                    &Ws[(size_t)((T * 8 + kt) * 64 + l) * 8]);
#pragma unroll
                for (int mt = 0; mt < 4; ++mt)
                    acc[mt * 8 + g * 2 + j] = __builtin_amdgcn_mfma_f32_16x16x32_f16(
                        a[mt], b, acc[mt * 8 + g * 2 + j], 0, 0, 0);
            }
        __builtin_amdgcn_sched_barrier(0);   // no motion across kt iterations
    }
}

// ---------------------------------------------------------------------------
// Persistent LSTM: block = 64 rows x 16 steps, 8 waves (512 threads).
// Corrected HW model: unified pool = 512 regs/SIMD; 8-wave block -> 256
// unified/wave = 128 arch + 128 AGPR(acc). R2-R10 spilled because arch
// demand sat AT the 128 cap (ledgers ran ~24 light: addr pairs + LICM'd
// W_lin float4s). R11 cuts arch demand ~50:
//   xp split: (f,o) gates in 32 regs, (i,g) gates in LDS (64 KB);
//   cx in LDS (64 KB); head W_lin loads de-LICM'd via opaque-pointer asm.
// Arch peak ~80 <= 128.  LDS: hx 32 + xp_ig 64 + cx 64 = 160 KB, 1 blk/CU.
// ---------------------------------------------------------------------------
__global__ __launch_bounds__(512)
void lstm_kernel(
    const float* __restrict__ x,      // [8][256][1600]
    const float* __restrict__ hx0,    // [12800][256]
    const float* __restrict__ cx0,    // [12800][256]
    const float* __restrict__ b_ih,   // [1024]
    const float* __restrict__ b_hh,   // [1024]
    const float* __restrict__ W_lin,  // [2][256]
    const float* __restrict__ b_lin,  // [2]
    const half_t* __restrict__ Wih_s, // shuffled f16
    const half_t* __restrict__ Whh_s, // shuffled f16
    float* __restrict__ out)          // [12800][16][2]
{
    __shared__ __align__(16) half_t lds_hx[64 * 256];        // 32 KB
    __shared__ __align__(16) half_t lds_xp[8 * 16 * 64 * 4]; // 64 KB (i,g xp)
    __shared__ __align__(16) float  cx_lds[32 * 512];        // 64 KB

    const int tid = threadIdx.x;
    const int w  = tid >> 6;   // wave 0..7 owns h-cols [w*32, w*32+32)
    const int l  = tid & 63;
    const int lm = l & 15;
    const int lg = l >> 4;

    const int row0 = blockIdx.x * 64;     // 200 blocks * 64 rows
    const int bb_  = row0 / 1600;
    const int p0   = row0 % 1600;

    // ---- stage x tile into lds_hx, f16 swizzled (coalesced on p) ----
    {
        const float* xin = x + (size_t)bb_ * 409600 + p0;   // x[b][c][p0+p]
        for (int it = 0; it < 32; ++it) {
            int idx = it * 512 + tid;
            int p = idx & 63, c = idx >> 6;
            lds_hx[p * 256 + (c ^ ((p & 7) << 4))] = (half_t)xin[c * 1600 + p];
        }
    }
    __syncthreads();

    f32x4 acc[32];

    // ---------------- phase 0: x_proj = x @ W_ih^T + b_ih + b_hh ----------
#pragma unroll
    for (int g = 0; g < 4; ++g)
#pragma unroll
        for (int j = 0; j < 2; ++j) {
            int col = g * 256 + (w * 2 + j) * 16 + lm;
            float bias = b_ih[col] + b_hh[col];
#pragma unroll
            for (int mt = 0; mt < 4; ++mt)
                acc[mt * 8 + g * 2 + j] = (f32x4){bias, bias, bias, bias};
        }
    gemm_all(acc, lds_hx, Wih_s, w, lm, lg, l);

    // split x_proj: (f,o) -> 32 regs; (i,g) -> LDS frag dump
    half4v xp_fo[16];   // fi = mt*4 + gi*2 + j, gi: 0=f(g1), 1=o(g3)
#pragma unroll
    for (int mt = 0; mt < 4; ++mt)
#pragma unroll
        for (int gi = 0; gi < 2; ++gi)
#pragma unroll
            for (int j = 0; j < 2; ++j) {
                half4v vf, vi;
#pragma unroll
                for (int r = 0; r < 4; ++r) {
                    vf[r] = (half_t)acc[mt * 8 + (gi ? 6 : 2) + j][r]; // f,o
                    vi[r] = (half_t)acc[mt * 8 + (gi ? 4 : 0) + j][r]; // i,g
                }
                xp_fo[mt * 4 + gi * 2 + j] = vf;
                int f = mt * 4 + gi * 2 + j;
                *reinterpret_cast<half4v*>(
                    &lds_xp[((w * 16 + f) * 64 + l) * 4]) = vi;
            }
    __syncthreads();   // x tile fully consumed; lds_hx reusable

    // ---- stage h0 into lds_hx (coalesced on c); cx into LDS slots ----
    {
        const float* hin = hx0 + (size_t)row0 * 256;
        for (int it = 0; it < 32; ++it) {
            int idx = it * 512 + tid;
            int c = idx & 255, p = idx >> 8;
            lds_hx[p * 256 + (c ^ ((p & 7) << 4))] = (half_t)hin[p * 256 + c];
        }
    }
#pragma unroll
    for (int mt = 0; mt < 4; ++mt)
#pragma unroll
        for (int j = 0; j < 2; ++j)
#pragma unroll
            for (int r = 0; r < 4; ++r) {
                int p = mt * 16 + lg * 4 + r;
                int c = w * 32 + j * 16 + lm;
                cx_lds[((mt * 2 + j) * 4 + r) * 512 + tid] =
                    cx0[(size_t)(row0 + p) * 256 + c];
            }
    const float blin0 = b_lin[0], blin1 = b_lin[1];
    __syncthreads();

    // ---------------- 16 recurrent steps ----------------
#pragma unroll 1
    for (int t = 0; t < 16; ++t) {
        // phase 1: acc init -- (f,o) from regs, (i,g) from LDS
#pragma unroll
        for (int mt = 0; mt < 4; ++mt)
#pragma unroll
            for (int gi = 0; gi < 2; ++gi)
#pragma unroll
                for (int j = 0; j < 2; ++j) {
                    int f = mt * 4 + gi * 2 + j;
                    half4v vf = xp_fo[f];
                    half4v vi = *reinterpret_cast<const half4v*>(
                        &lds_xp[((w * 16 + f) * 64 + l) * 4]);
#pragma unroll
                    for (int r = 0; r < 4; ++r) {
                        acc[mt * 8 + (gi ? 6 : 2) + j][r] = (float)vf[r];
                        acc[mt * 8 + (gi ? 4 : 0) + j][r] = (float)vi[r];
                    }
                }
        __builtin_amdgcn_sched_barrier(0);

        // phase 2: GEMM (kt-pinned inside)
        gemm_all(acc, lds_hx, Whh_s, w, lm, lg, l);

        __syncthreads();   // all waves finished reading lds_hx(t)

        // phase 3: cell update; cx in LDS slots; hx(t+1) -> lds_hx swizzled
#pragma unroll
        for (int mt = 0; mt < 4; ++mt)
#pragma unroll
            for (int j = 0; j < 2; ++j)
#pragma unroll
                for (int r = 0; r < 4; ++r) {
                    const int slot = ((mt * 2 + j) * 4 + r) * 512 + tid;
                    float iv = acc[mt * 8 + 0 + j][r];
                    float fv = acc[mt * 8 + 2 + j][r];
                    float gv = acc[mt * 8 + 4 + j][r];
                    float ov = acc[mt * 8 + 6 + j][r];
                    float cxn = fast_sigmoid(fv) * cx_lds[slot] +
                                fast_sigmoid(iv) * fast_tanh(gv);
                    cx_lds[slot] = cxn;
                    float h = fast_sigmoid(ov) * fast_tanh(cxn);
                    int p  = mt * 16 + lg * 4 + r;
                    int cc = w * 32 + j * 16 + lm;
                    lds_hx[p * 256 + (cc ^ ((p & 7) << 4))] = (half_t)h;
                }
        __syncthreads();   // hx(t+1) visible to all

        // phase 4: head y = leaky_relu(hx) @ W_lin^T + b_lin -> [n][t][o]
        {
            const int p = tid >> 3;          // row 0..63
            const int o = (tid >> 2) & 1;    // output 0..1
            const int q = tid & 3;           // quarter of the 256 h-cols
            // opaque pointer: defeat LICM of the 8 float4 W_lin loads
            // (32 regs held across the whole t-loop otherwise)
            const float* wl = W_lin + o * 256 + q * 64;
            asm volatile("" : "+v"(wl));
            float s = 0.0f;
#pragma unroll 2
            for (int cb = 0; cb < 16; ++cb) {
                int c0 = q * 64 + cb * 4;
                half4v u = *reinterpret_cast<const half4v*>(
                    &lds_hx[p * 256 + (c0 ^ ((p & 7) << 4))]);
                float4 wv = *reinterpret_cast<const float4*>(wl + cb * 4);
                float h0 = (float)u[0], h1 = (float)u[1];
                float h2 = (float)u[2], h3 = (float)u[3];
                s += fmaxf(h0, 0.01f * h0) * wv.x;
                s += fmaxf(h1, 0.01f * h1) * wv.y;
                s += fmaxf(h2, 0.01f * h2) * wv.z;
                s += fmaxf(h3, 0.01f * h3) * wv.w;
            }
            s += __shfl_xor(s, 1);
            s += __shfl_xor(s, 2);
            if (q == 0)
                out[((size_t)(row0 + p) * 16 + t) * 2 + o] =
                    s + (o ? blin1 : blin0);
        }
    }
}

// ---------------------------------------------------------------------------
extern "C" void kernel_launch(void* const* d_in, const int* in_sizes, int n_in,
                              void* d_out, int out_size, void* d_ws, size_t ws_size,
                              hipStream_t stream)
{
    const float* x    = (const float*)d_in[0];
    const float* hx   = (const float*)d_in[1];
    const float* cx   = (const float*)d_in[2];
    const float* Wih  = (const float*)d_in[3];
    const float* Whh  = (const float*)d_in[4];
    const float* bih  = (const float*)d_in[5];
    const float* bhh  = (const float*)d_in[6];
    const float* Wlin = (const float*)d_in[7];
    const float* blin = (const float*)d_in[8];
    float* out = (float*)d_out;

    half_t* wih_s = (half_t*)d_ws;             // 512 KB
    half_t* whh_s = wih_s + 1024 * 256;        // 512 KB

    shuffle_w_kernel<<<512, 64, 0, stream>>>(Wih, wih_s);
    shuffle_w_kernel<<<512, 64, 0, stream>>>(Whh, whh_s);
    lstm_kernel<<<200, 512, 0, stream>>>(x, hx, cx, bih, bhh, Wlin, blin,
                                         wih_s, whh_s, out);
}

// Round 12
// 284.278 us; speedup vs baseline: 1.8584x; 1.1286x over previous
//
#include <hip/hip_runtime.h>
#include <stdint.h>
#include <stddef.h>

// ---------- types ----------
typedef _Float16 half_t;
typedef half_t half8  __attribute__((ext_vector_type(8)));
typedef half_t half4v __attribute__((ext_vector_type(4)));
typedef float  f32x4  __attribute__((ext_vector_type(4)));

__device__ __forceinline__ float fast_sigmoid(float x) {
    float e = __builtin_amdgcn_exp2f(-1.44269504f * x);
    return __builtin_amdgcn_rcpf(1.0f + e);
}
__device__ __forceinline__ float fast_tanh(float x) {
    float e = __builtin_amdgcn_exp2f(2.88539008f * x);
    return 1.0f - 2.0f * __builtin_amdgcn_rcpf(1.0f + e);
}

// ---------------------------------------------------------------------------
// Prep: W [1024][256] f32 row-major -> MFMA-B fragment order, f16.
// Bijection (contiguous k): lane l, elem e of tile (T,kt) holds
//   B[k = kt*32 + (l>>4)*8 + e, j = T*16 + (l&15)].
// A-fragments from LDS use the SAME (lane-group,elem)->k mapping (validated
// R1-R11: absmax 2e-3).
// ---------------------------------------------------------------------------
__global__ __launch_bounds__(64) void shuffle_w_kernel(
    const float* __restrict__ W, half_t* __restrict__ out)
{
    const int blk = blockIdx.x;         // 512 = 64 T * 8 kt
    const int T = blk >> 3, kt = blk & 7;
    const int l = threadIdx.x;
    const int j = T * 16 + (l & 15);
    const int k0 = kt * 32 + ((l >> 4) << 3);
    half8 v;
#pragma unroll
    for (int e = 0; e < 8; ++e) v[e] = (half_t)W[j * 256 + k0 + e];
    *reinterpret_cast<half8*>(out + (size_t)(blk * 64 + l) * 8) = v;
}

// ---------------------------------------------------------------------------
// 2-gate (4 N-tile) GEMM pass with B double-buffer prefetch:
//   acc[mt*4 + n] += hx(64x256) @ W^T tile {Ta,Tb,Tc,Td}[n].
// kt loop pinned (unroll 1 + sched_barrier at each sub-step) -- proven
// anti-hoist (R4-R11) -- but b(kt+1) is issued BEFORE the MFMAs of kt
// within the fence window, so L2 latency hides under the 16-MFMA block.
// In-flight: acc 64 + bA/bB 32 + a 16 + bp addrs 8.
// ---------------------------------------------------------------------------
__device__ __forceinline__ void gemm_pass(
    f32x4* acc, const half_t* __restrict__ lhx,
    const half_t* __restrict__ Ws, int Ta, int Tb, int Tc, int Td,
    int lm, int lg, int l)
{
    const half_t* bp[4] = {
        Ws + (size_t)((Ta * 8) * 64 + l) * 8,
        Ws + (size_t)((Tb * 8) * 64 + l) * 8,
        Ws + (size_t)((Tc * 8) * 64 + l) * 8,
        Ws + (size_t)((Td * 8) * 64 + l) * 8 };
    half8 bA[4], bB[4];
#pragma unroll
    for (int n = 0; n < 4; ++n) bA[n] = *reinterpret_cast<const half8*>(bp[n]);

#pragma unroll 1
    for (int kt2 = 0; kt2 < 4; ++kt2) {
        const int kt = kt2 * 2;
        // prefetch b(kt+1); MFMA(kt) with bA
#pragma unroll
        for (int n = 0; n < 4; ++n)
            bB[n] = *reinterpret_cast<const half8*>(bp[n] + (kt + 1) * 512);
        {
            half8 a[4];
#pragma unroll
            for (int mt = 0; mt < 4; ++mt) {
                const int p = mt * 16 + lm;
                const int k = (kt * 32 + lg * 8) ^ ((p & 7) << 4);
                a[mt] = *reinterpret_cast<const half8*>(&lhx[p * 256 + k]);
            }
#pragma unroll
            for (int n = 0; n < 4; ++n)
#pragma unroll
                for (int mt = 0; mt < 4; ++mt)
                    acc[mt * 4 + n] = __builtin_amdgcn_mfma_f32_16x16x32_f16(
                        a[mt], bA[n], acc[mt * 4 + n], 0, 0, 0);
        }
        __builtin_amdgcn_sched_barrier(0);
        // prefetch b(kt+2) (wraps at end: harmless); MFMA(kt+1) with bB
#pragma unroll
        for (int n = 0; n < 4; ++n)
            bA[n] = *reinterpret_cast<const half8*>(bp[n] + ((kt + 2) & 7) * 512);
        {
            half8 a[4];
#pragma unroll
            for (int mt = 0; mt < 4; ++mt) {
                const int p = mt * 16 + lm;
                const int k = ((kt + 1) * 32 + lg * 8) ^ ((p & 7) << 4);
                a[mt] = *reinterpret_cast<const half8*>(&lhx[p * 256 + k]);
            }
#pragma unroll
            for (int n = 0; n < 4; ++n)
#pragma unroll
                for (int mt = 0; mt < 4; ++mt)
                    acc[mt * 4 + n] = __builtin_amdgcn_mfma_f32_16x16x32_f16(
                        a[mt], bB[n], acc[mt * 4 + n], 0, 0, 0);
        }
        __builtin_amdgcn_sched_barrier(0);
    }
}

// ---------------------------------------------------------------------------
// Persistent LSTM: block = 64 rows x 16 steps, 8 waves (512 threads).
// Unified-register model (R11 post-mortem): budget = 256/wave total
// (2 waves/SIMD x 512-reg pool); R11 demand ~260 -> persistent spill.
// R12 cuts demand via 2-pass gate split (R5-validated numerics):
//   pass A (f,o): cxr *= sig(f), stash o-preact f16; pass B (i,g): finish.
//   acc[16]=64, cxr 32, og 16, B dbuf 32, a 16, addr/misc ~35  => ~195.
// xp entirely in LDS: hx 32 KB + xp 128 KB = 160 KB, 1 blk/CU.
// ---------------------------------------------------------------------------
__global__ __launch_bounds__(512)
void lstm_kernel(
    const float* __restrict__ x,      // [8][256][1600]
    const float* __restrict__ hx0,    // [12800][256]
    const float* __restrict__ cx0,    // [12800][256]
    const float* __restrict__ b_ih,   // [1024]
    const float* __restrict__ b_hh,   // [1024]
    const float* __restrict__ W_lin,  // [2][256]
    const float* __restrict__ b_lin,  // [2]
    const half_t* __restrict__ Wih_s, // shuffled f16
    const half_t* __restrict__ Whh_s, // shuffled f16
    float* __restrict__ out)          // [12800][16][2]
{
    __shared__ __align__(16) half_t lds_hx[64 * 256];        // 32 KB
    __shared__ __align__(16) half_t lds_xp[8 * 32 * 64 * 4]; // 128 KB

    const int tid = threadIdx.x;
    const int w  = tid >> 6;   // wave 0..7 owns h-cols [w*32, w*32+32)
    const int l  = tid & 63;
    const int lm = l & 15;
    const int lg = l >> 4;
    const int w2 = w * 2;

    const int row0 = blockIdx.x * 64;     // 200 blocks * 64 rows
    const int bb_  = row0 / 1600;
    const int p0   = row0 % 1600;

    // ---- stage x tile into lds_hx, f16 swizzled (coalesced on p) ----
    {
        const float* xin = x + (size_t)bb_ * 409600 + p0;   // x[b][c][p0+p]
        for (int it = 0; it < 32; ++it) {
            int idx = it * 512 + tid;
            int p = idx & 63, c = idx >> 6;
            lds_hx[p * 256 + (c ^ ((p & 7) << 4))] = (half_t)xin[c * 1600 + p];
        }
    }
    __syncthreads();

    f32x4 acc[16];

    // ---- phase 0: x_proj = x @ W_ih^T + b_ih + b_hh, 2 passes -> LDS ----
#pragma unroll 1
    for (int pass = 0; pass < 2; ++pass) {
        const int gA = pass ? 0 : 1, gB = pass ? 2 : 3;   // pass0:(f,o) pass1:(i,g)
        const int Ta = gA * 16 + w2, Tb = Ta + 1;
        const int Tc = gB * 16 + w2, Td = Tc + 1;
        const int Tt[4] = {Ta, Tb, Tc, Td};
#pragma unroll
        for (int n = 0; n < 4; ++n) {
            int col = Tt[n] * 16 + lm;
            float bias = b_ih[col] + b_hh[col];
#pragma unroll
            for (int mt = 0; mt < 4; ++mt)
                acc[mt * 4 + n] = (f32x4){bias, bias, bias, bias};
        }
        gemm_pass(acc, lds_hx, Wih_s, Ta, Tb, Tc, Td, lm, lg, l);
#pragma unroll
        for (int f = 0; f < 16; ++f) {
            half4v xv;
#pragma unroll
            for (int r = 0; r < 4; ++r) xv[r] = (half_t)acc[f][r];
            *reinterpret_cast<half4v*>(
                &lds_xp[((w * 32 + pass * 16 + f) * 64 + l) * 4]) = xv;
        }
    }
    __syncthreads();   // x tile fully consumed, xp written

    // ---- stage h0 into lds_hx (coalesced on c); cx into registers ----
    {
        const float* hin = hx0 + (size_t)row0 * 256;
        for (int it = 0; it < 32; ++it) {
            int idx = it * 512 + tid;
            int c = idx & 255, p = idx >> 8;
            lds_hx[p * 256 + (c ^ ((p & 7) << 4))] = (half_t)hin[p * 256 + c];
        }
    }
    float cxr[32];
#pragma unroll
    for (int mt = 0; mt < 4; ++mt)
#pragma unroll
        for (int j = 0; j < 2; ++j)
#pragma unroll
            for (int r = 0; r < 4; ++r) {
                int p = mt * 16 + lg * 4 + r;
                int c = w * 32 + j * 16 + lm;
                cxr[(mt * 2 + j) * 4 + r] = cx0[(size_t)(row0 + p) * 256 + c];
            }
    const float blin0 = b_lin[0], blin1 = b_lin[1];
    __syncthreads();

    // ---------------- 16 recurrent steps ----------------
#pragma unroll 1
    for (int t = 0; t < 16; ++t) {
        half4v og[8];   // o-gate preactivations, f16 (R5-validated)

        // ---- pass A: gates (f,o) ----
#pragma unroll
        for (int f = 0; f < 16; ++f) {
            half4v u = *reinterpret_cast<const half4v*>(
                &lds_xp[((w * 32 + f) * 64 + l) * 4]);
#pragma unroll
            for (int r = 0; r < 4; ++r) acc[f][r] = (float)u[r];
        }
        __builtin_amdgcn_sched_barrier(0);
        gemm_pass(acc, lds_hx, Whh_s, 16 + w2, 17 + w2, 48 + w2, 49 + w2,
                  lm, lg, l);
#pragma unroll
        for (int mt = 0; mt < 4; ++mt)
#pragma unroll
            for (int j = 0; j < 2; ++j)
#pragma unroll
                for (int r = 0; r < 4; ++r) {
                    float fv = acc[mt * 4 + 0 + j][r];
                    float ov = acc[mt * 4 + 2 + j][r];
                    cxr[(mt * 2 + j) * 4 + r] *= fast_sigmoid(fv);
                    og[mt * 2 + j][r] = (half_t)ov;
                }
        __builtin_amdgcn_sched_barrier(0);

        // ---- pass B: gates (i,g) ----
#pragma unroll
        for (int f = 0; f < 16; ++f) {
            half4v u = *reinterpret_cast<const half4v*>(
                &lds_xp[((w * 32 + 16 + f) * 64 + l) * 4]);
#pragma unroll
            for (int r = 0; r < 4; ++r) acc[f][r] = (float)u[r];
        }
        __builtin_amdgcn_sched_barrier(0);
        gemm_pass(acc, lds_hx, Whh_s, w2, w2 + 1, 32 + w2, 33 + w2,
                  lm, lg, l);

        __syncthreads();   // all waves finished reading lds_hx(t)

        // cell update; write hx(t+1) into lds_hx (f16, swizzled)
#pragma unroll
        for (int mt = 0; mt < 4; ++mt)
#pragma unroll
            for (int j = 0; j < 2; ++j)
#pragma unroll
                for (int r = 0; r < 4; ++r) {
                    const int ci = (mt * 2 + j) * 4 + r;
                    float iv = acc[mt * 4 + 0 + j][r];
                    float gv = acc[mt * 4 + 2 + j][r];
                    float cxn = cxr[ci] + fast_sigmoid(iv) * fast_tanh(gv);
                    cxr[ci] = cxn;
                    float so = fast_sigmoid((float)og[mt * 2 + j][r]);
                    float h = so * fast_tanh(cxn);
                    int p  = mt * 16 + lg * 4 + r;
                    int cc = w * 32 + j * 16 + lm;
                    lds_hx[p * 256 + (cc ^ ((p & 7) << 4))] = (half_t)h;
                }
        __syncthreads();   // hx(t+1) visible to all

        // head: y = leaky_relu(hx) @ W_lin^T + b_lin -> [n][t][o]
        {
            const int p = tid >> 3;          // row 0..63
            const int o = (tid >> 2) & 1;    // output 0..1
            const int q = tid & 3;           // quarter of the 256 h-cols
            const float* wl = W_lin + o * 256 + q * 64;
            asm volatile("" : "+v"(wl));     // defeat 32-reg W_lin LICM
            float s = 0.0f;
#pragma unroll 2
            for (int cb = 0; cb < 16; ++cb) {
                int c0 = q * 64 + cb * 4;
                half4v u = *reinterpret_cast<const half4v*>(
                    &lds_hx[p * 256 + (c0 ^ ((p & 7) << 4))]);
                float4 wv = *reinterpret_cast<const float4*>(wl + cb * 4);
                float h0 = (float)u[0], h1 = (float)u[1];
                float h2 = (float)u[2], h3 = (float)u[3];
                s += fmaxf(h0, 0.01f * h0) * wv.x;
                s += fmaxf(h1, 0.01f * h1) * wv.y;
                s += fmaxf(h2, 0.01f * h2) * wv.z;
                s += fmaxf(h3, 0.01f * h3) * wv.w;
            }
            s += __shfl_xor(s, 1);
            s += __shfl_xor(s, 2);
            if (q == 0)
                out[((size_t)(row0 + p) * 16 + t) * 2 + o] =
                    s + (o ? blin1 : blin0);
        }
    }
}

// ---------------------------------------------------------------------------
extern "C" void kernel_launch(void* const* d_in, const int* in_sizes, int n_in,
                              void* d_out, int out_size, void* d_ws, size_t ws_size,
                              hipStream_t stream)
{
    const float* x    = (const float*)d_in[0];
    const float* hx   = (const float*)d_in[1];
    const float* cx   = (const float*)d_in[2];
    const float* Wih  = (const float*)d_in[3];
    const float* Whh  = (const float*)d_in[4];
    const float* bih  = (const float*)d_in[5];
    const float* bhh  = (const float*)d_in[6];
    const float* Wlin = (const float*)d_in[7];
    const float* blin = (const float*)d_in[8];
    float* out = (float*)d_out;

    half_t* wih_s = (half_t*)d_ws;             // 512 KB
    half_t* whh_s = wih_s + 1024 * 256;        // 512 KB

    shuffle_w_kernel<<<512, 64, 0, stream>>>(Wih, wih_s);
    shuffle_w_kernel<<<512, 64, 0, stream>>>(Whh, whh_s);
    lstm_kernel<<<200, 512, 0, stream>>>(x, hx, cx, bih, bhh, Wlin, blin,
                                         wih_s, whh_s, out);
}